// Round 8
// baseline (181.221 us; speedup 1.0000x reference)
//
#include <hip/hip_runtime.h>

// Conv2d 32x128x56x56 -> 32x256x56x56, 3x3, pad 1, stride 1. fp32 I/O.
// Implicit GEMM, bf16 mfma_f32_16x16x32. Fused: conv stages straight from
// NCHW fp32 (no X2 intermediate); W2[step][co][ci_lo] prepped separately.
// ROUND 8: revert R7's B ping-pong (rocprof: conv 104us, MfmaUtil 22 --
// the (s&1) selects + an->a copies broke the schedule). Instead:
//  1) TWO-STEP B BATCHING, flat b[14], strictly static indexing, no
//     copies: each pair-iteration reads 14 b-frags (steps s, s+1), then
//     runs 2x28 MFMAs. Halves lgkm wait-points (36 -> 18); each wait is
//     covered by ~1086 cy of MFMA instead of ~543.
//  2) A-prologue: a(step 0) issued from W2 BEFORE staging+barrier (W2
//     doesn't depend on Xs) -- kills the cold-W2 first-step stall (R7's
//     183us cold dispatch).
//  3) Everything else = R5 exactly: register-transpose staging (wave wv
//     owns input row h0-1+wv, lane owns pixel; 16 rounds of 8 coalesced
//     f32 loads -> RNE pack -> ds_write_b128), RSTR=136 (272B, measured
//     best), ONE barrier, XCD swizzle (112 tiles = 4 images per XCD).
// Block: 256 thr = 4 waves, tile 256co x 112p (2 output rows). Wave: 4m x 7n.
// Regs: 112 acc + 56 b + 32 a/an + ~25 addr ~= 225 < 256 -> 2 waves/SIMD.

#define CIN   128
#define COUT  256
#define HWID  56
#define IMG   (HWID*HWID)     // 3136
#define NIMG  32
#define RSTR  136             // Xs pixel stride in shorts (272B, 16B-aligned)

typedef __attribute__((ext_vector_type(8))) short short8;   // 8 bf16 = 4 VGPRs
typedef __attribute__((ext_vector_type(4))) float float4v;  // MFMA acc

__device__ __forceinline__ unsigned short f2bf(float f) {
    unsigned int u = __builtin_bit_cast(unsigned int, f);
    u += 0x7FFFu + ((u >> 16) & 1u);   // RNE
    return (unsigned short)(u >> 16);
}

// W2[((ci_hi*9 + kh*3 + kw)*256 + co)*32 + ci_lo] = bf16(w[co][ci_hi*32+ci_lo][kh][kw])
__global__ __launch_bounds__(256) void prep_w_kernel(const float* __restrict__ w,
                                                     unsigned short* __restrict__ W2) {
    int o = blockIdx.x * 256 + threadIdx.x;        // 294912 total
    int ci_lo = o & 31;
    int co    = (o >> 5) & 255;
    int s     = o >> 13;                           // 0..35
    int ci_hi = s / 9;
    int r9    = s - ci_hi * 9;                     // kh*3+kw
    W2[o] = f2bf(w[(co * CIN + ci_hi * 32 + ci_lo) * 9 + r9]);
}

__global__ __launch_bounds__(256, 2)
void conv_mfma_kernel(const float* __restrict__ x,
                      const unsigned short* __restrict__ W2,
                      float* __restrict__ out) {
    __shared__ __align__(16) unsigned short Xs[232 * RSTR];   // 63104 B

    const int tid  = threadIdx.x;
    const int lane = tid & 63;
    const int wv   = tid >> 6;
    const int l15  = lane & 15;
    const int quad = lane >> 4;

    // XCD swizzle: give each XCD a contiguous 112-tile chunk (4 whole images).
    const int pt    = (blockIdx.x & 7) * 112 + (blockIdx.x >> 3);   // 0..895
    const int n_img = pt / 28;
    const int h0    = (pt % 28) * 2;   // output rows h0, h0+1

    // a-frag base: W2[step][co][ci_lo], co = wv*64 + m*16 + l15, ci_lo = quad*8+j
    const unsigned short* wbase = W2 + (wv * 64 + l15) * 32 + quad * 8;

    // ---- A-prologue: step 0's A-frags issued BEFORE staging/barrier ----
    short8 a[4], an[4];
    #pragma unroll
    for (int m = 0; m < 4; ++m)
        a[m] = *(const short8*)(wbase + m * 512);

    // ---- fused staging: register transpose, no scratch LDS ----
    // wave wv: input row h = h0-1+wv. lane: pixel w = lane-1 (c = lane).
    {
        const int h     = h0 - 1 + wv;
        const int wpix  = lane - 1;
        const bool vald = ((unsigned)h < 56u) & ((unsigned)wpix < 56u);
        const float* xcol = x + ((long)n_img * CIN) * IMG + h * HWID + wpix;
        const int rc = wv * 58 + lane;

        if (lane < 58) {
            #pragma unroll
            for (int c8 = 0; c8 < 16; ++c8) {
                short8 o = (short8){0,0,0,0,0,0,0,0};
                if (vald) {
                    float v0 = xcol[(c8*8 + 0) * IMG];
                    float v1 = xcol[(c8*8 + 1) * IMG];
                    float v2 = xcol[(c8*8 + 2) * IMG];
                    float v3 = xcol[(c8*8 + 3) * IMG];
                    float v4 = xcol[(c8*8 + 4) * IMG];
                    float v5 = xcol[(c8*8 + 5) * IMG];
                    float v6 = xcol[(c8*8 + 6) * IMG];
                    float v7 = xcol[(c8*8 + 7) * IMG];
                    unsigned int* op = (unsigned int*)&o;
                    op[0] = (unsigned int)f2bf(v0) | ((unsigned int)f2bf(v1) << 16);
                    op[1] = (unsigned int)f2bf(v2) | ((unsigned int)f2bf(v3) << 16);
                    op[2] = (unsigned int)f2bf(v4) | ((unsigned int)f2bf(v5) << 16);
                    op[3] = (unsigned int)f2bf(v6) | ((unsigned int)f2bf(v7) << 16);
                }
                *(short8*)(&Xs[rc * RSTR + c8 * 8]) = o;
            }
        }
    }
    __syncthreads();   // the only barrier

    // per-lane b-frag pixel bases, one per n-tile
    int boff[7];
    #pragma unroll
    for (int n = 0; n < 7; ++n) {
        int p    = n * 16 + l15;
        int prow = (p >= 56) ? 1 : 0;
        int pcol = p - prow * 56;
        boff[n]  = (prow * 58 + pcol) * RSTR + quad * 8;
    }

    float4v acc[4][7];
    #pragma unroll
    for (int m = 0; m < 4; ++m)
        #pragma unroll
        for (int n = 0; n < 7; ++n)
            acc[m][n] = (float4v){0.f, 0.f, 0.f, 0.f};

    // ---- 18 pair-steps, NO barriers. Per pair (steps s, s+1):
    //   read 14 b-frags, prefetch A(s+1), 28 MFMA, prefetch A(s+2),
    //   28 MFMA. All indices compile-time (full unroll). ----
    #pragma unroll
    for (int s2 = 0; s2 < 18; ++s2) {
        const int s0 = 2 * s2;
        short8 b[14];
        #pragma unroll
        for (int half = 0; half < 2; ++half) {
            const int s     = s0 + half;
            const int ci_hi = s / 9;
            const int khw   = s % 9;
            const int kh = khw / 3, kw = khw - kh * 3;
            const int xoff = (kh * 58 + kw) * RSTR + ci_hi * 32;
            #pragma unroll
            for (int n = 0; n < 7; ++n)
                b[half * 7 + n] = *(const short8*)(&Xs[boff[n] + xoff]);
        }
        // prefetch A(s0+1)
        #pragma unroll
        for (int m = 0; m < 4; ++m)
            an[m] = *(const short8*)(wbase + (s0 + 1) * 8192 + m * 512);
        // MFMAs for step s0
        #pragma unroll
        for (int m = 0; m < 4; ++m)
            #pragma unroll
            for (int n = 0; n < 7; ++n)
                acc[m][n] = __builtin_amdgcn_mfma_f32_16x16x32_bf16(a[m], b[n], acc[m][n], 0, 0, 0);
        #pragma unroll
        for (int m = 0; m < 4; ++m)
            a[m] = an[m];
        // prefetch A(s0+2) for next pair
        if (s2 < 17) {
            #pragma unroll
            for (int m = 0; m < 4; ++m)
                an[m] = *(const short8*)(wbase + (s0 + 2) * 8192 + m * 512);
        }
        // MFMAs for step s0+1
        #pragma unroll
        for (int m = 0; m < 4; ++m)
            #pragma unroll
            for (int n = 0; n < 7; ++n)
                acc[m][n] = __builtin_amdgcn_mfma_f32_16x16x32_bf16(a[m], b[7 + n], acc[m][n], 0, 0, 0);
        if (s2 < 17) {
            #pragma unroll
            for (int m = 0; m < 4; ++m)
                a[m] = an[m];
        }
    }

    // ---- epilogue: C/D layout col(p)=lane&15, row(co)=quad*4+reg ----
    float* obase = out + (long)n_img * (COUT * IMG) + h0 * HWID;
    #pragma unroll
    for (int m = 0; m < 4; ++m) {
        #pragma unroll
        for (int r = 0; r < 4; ++r) {
            int co = wv * 64 + m * 16 + quad * 4 + r;
            float* orow = obase + (long)co * IMG;
            #pragma unroll
            for (int n = 0; n < 7; ++n)
                orow[n * 16 + l15] = acc[m][n][r];
        }
    }
}

extern "C" void kernel_launch(void* const* d_in, const int* in_sizes, int n_in,
                              void* d_out, int out_size, void* d_ws, size_t ws_size,
                              hipStream_t stream) {
    const float* x  = (const float*)d_in[0];
    const float* wt = (const float*)d_in[1];
    float* out = (float*)d_out;

    unsigned short* W2 = (unsigned short*)d_ws;   // 294,912 shorts

    prep_w_kernel<<<(COUT * CIN * 9) / 256, 256, 0, stream>>>(wt, W2);
    conv_mfma_kernel<<<NIMG * 28, 256, 0, stream>>>(x, W2, out);
}